// Round 11
// baseline (213.104 us; speedup 1.0000x reference)
//
#include <hip/hip_runtime.h>

// HybridLoss: param smooth-L1 mean + 0.5*(1 - mean(box overlap))
// B = 2,000,000 rows x 10 f32 (c[3], d[3], q[4]) per side.
//
// R3:  per-row direct loads -> transaction-bound (40-B rows vs 64-B lines), 76us.
// R5:  global_load_lds, tiny blocks, no overlap -> latency-bound, 112us.
// R6:  reg-staged pipeline -> 40 prefetch VGPRs spilled (152 MB scratch), 97us.
// R10: runtime-indexed LDS double buffer -> compiler can't prove
//      gload_lds(buf cur^1) doesn't alias ds_read(buf cur) -> it drains
//      vmcnt(0) BEFORE compute -> zero overlap again, 73.5us, VALU 22%.
// R11 (this): STATIC even/odd double buffer (4 named __shared__ arrays,
//      2x-unrolled loop, compile-time buffer choice) -> provably disjoint
//      LDS objects -> vmcnt wait sinks to the barrier -> loads overlap the
//      full compute phase. 128-thread blocks, 8 pipelines/CU.

#define B_ROWS 2000000
#define THREADS 128
#define CHUNK_ROWS 128
#define F4_SIDE 320                    // 128 rows * 40 B / 16 B per side
#define N_CHUNKS 15625                 // 2e6 / 128 exactly (no tail!)
#define GRID 2048                      // persistent, 8 blocks/CU (LDS 20480 B)
constexpr float OVERLAP_WEIGHT = 0.5f;
constexpr float EPS_F = 1e-6f;

__device__ __forceinline__ void gload_lds16(const float4* g, float4* l) {
    // LDS dest is wave-uniform; HW writes lane i at dest + i*16.
    __builtin_amdgcn_global_load_lds(
        (const __attribute__((address_space(1))) void*)g,
        (__attribute__((address_space(3))) void*)l, 16, 0, 0);
}

__device__ __forceinline__ void quat_to_rot(float x, float y, float z, float w,
                                            float R[9]) {
    R[0] = 1.f - 2.f*y*y - 2.f*z*z;
    R[1] = 2.f*x*y + 2.f*z*w;
    R[2] = 2.f*x*z - 2.f*y*w;
    R[3] = 2.f*x*y - 2.f*z*w;
    R[4] = 1.f - 2.f*x*x - 2.f*z*z;
    R[5] = 2.f*y*z + 2.f*x*w;
    R[6] = 2.f*x*z + 2.f*y*w;
    R[7] = 2.f*y*z - 2.f*x*w;
    R[8] = 1.f - 2.f*x*x - 2.f*y*y;
}

__global__ __launch_bounds__(THREADS, 4) void hybrid_loss_main(
    const float4* __restrict__ preds4, const float4* __restrict__ targets4,
    float* __restrict__ acc)  // acc[0] = smooth-L1 sum, acc[1] = overlap sum
{
    // Four STATICALLY-NAMED buffers: compiler can prove gload writes to
    // {P1,T1} are disjoint from ds_reads of {P0,T0} (and vice versa).
    // 4 * 320 * 16 B = 20480 B -> 8 blocks/CU.
    __shared__ __align__(16) float4 P0[F4_SIDE], T0[F4_SIDE];
    __shared__ __align__(16) float4 P1[F4_SIDE], T1[F4_SIDE];

    const int tid  = threadIdx.x;
    const int wave = tid >> 6;
    const int lane = tid & 63;

    float psum = 0.f, osum = 0.f;

    // wave 0 stages preds, wave 1 stages targets: 5 gloads each, static unroll
    auto stage = [&](float4* LP, float4* LT, int c) {
        const int gb = c * F4_SIDE + lane;
        if (wave == 0) {
            #pragma unroll
            for (int r = 0; r < 5; ++r)
                gload_lds16(preds4 + gb + r * 64, LP + r * 64);
        } else {
            #pragma unroll
            for (int r = 0; r < 5; ++r)
                gload_lds16(targets4 + gb + r * 64, LT + r * 64);
        }
    };

    auto compute = [&](const float4* LP, const float4* LT) {
        // exact fit: N_CHUNKS*CHUNK_ROWS == B_ROWS, no row guard needed
        float p[10], t[10];
        const float2* lp = reinterpret_cast<const float2*>(
            reinterpret_cast<const float*>(LP) + tid * 10);
        const float2* lt = reinterpret_cast<const float2*>(
            reinterpret_cast<const float*>(LT) + tid * 10);
        #pragma unroll
        for (int i = 0; i < 5; ++i) {
            float2 a = lp[i]; p[2*i] = a.x; p[2*i+1] = a.y;
            float2 b = lt[i]; t[2*i] = b.x; t[2*i+1] = b.y;
        }

        // smooth L1
        #pragma unroll
        for (int i = 0; i < 10; ++i) {
            float d  = p[i] - t[i];
            float ad = fabsf(d);
            psum += (ad < 1.f) ? 0.5f * d * d : ad - 0.5f;
        }

        // overlap
        float pqn = sqrtf(p[6]*p[6] + p[7]*p[7] + p[8]*p[8] + p[9]*p[9]);
        float tqn = sqrtf(t[6]*t[6] + t[7]*t[7] + t[8]*t[8] + t[9]*t[9]);
        float pri = 1.f / pqn, tri = 1.f / tqn;
        float PR[9], TR[9];
        quat_to_rot(p[6]*pri, p[7]*pri, p[8]*pri, p[9]*pri, PR);
        quat_to_rot(t[6]*tri, t[7]*tri, t[8]*tri, t[9]*tri, TR);

        float ra = 0.f;
        #pragma unroll
        for (int i = 0; i < 9; ++i) ra += PR[i] * TR[i];
        ra = fminf(fmaxf(ra * (1.f/3.f), 0.f), 1.f);

        float ov = ra;
        #pragma unroll
        for (int i = 0; i < 3; ++i) {
            float pe = fabsf(PR[3*i+0]*(p[3]*0.5f) + PR[3*i+1]*(p[4]*0.5f) + PR[3*i+2]*(p[5]*0.5f));
            float te = fabsf(TR[3*i+0]*(t[3]*0.5f) + TR[3*i+1]*(t[4]*0.5f) + TR[3*i+2]*(t[5]*0.5f));
            float cd = fabsf(p[i] - t[i]);
            float ax = fmaxf(fminf(pe, te) * 2.f - cd, 0.f) / (pe + te + EPS_F);
            ov *= ax;
        }
        ov = fminf(fmaxf(ov, 0.f), 1.f);
        osum += ov;
    };

    // ---- software pipeline, compile-time even/odd buffers ----
    int c0 = blockIdx.x;
    stage(P0, T0, c0);
    __syncthreads();                     // prologue drain (once)
    int c1 = c0 + GRID;

    for (;;) {
        // phase A: stage buf1(c1) || compute buf0(c0)
        if (c1 < N_CHUNKS) stage(P1, T1, c1);      // block-uniform branch
        compute(P0, T0);
        __syncthreads();
        if (c1 >= N_CHUNKS) break;
        c0 = c1 + GRID;

        // phase B: stage buf0(c0) || compute buf1(c1)
        if (c0 < N_CHUNKS) stage(P0, T0, c0);
        compute(P1, T1);
        __syncthreads();
        if (c0 >= N_CHUNKS) break;
        c1 = c0 + GRID;
    }

    // ---- reduction: wave shuffle, cross-wave via reused LDS ----
    #pragma unroll
    for (int off = 32; off > 0; off >>= 1) {
        psum += __shfl_down(psum, off);
        osum += __shfl_down(osum, off);
    }
    float* red = reinterpret_cast<float*>(P0);     // post-barrier safe
    if (lane == 0) { red[wave] = psum; red[2 + wave] = osum; }
    __syncthreads();
    if (tid == 0) {
        atomicAdd(&acc[0], red[0] + red[1]);
        atomicAdd(&acc[1], red[2] + red[3]);
    }
}

__global__ void hybrid_loss_finalize(const float* __restrict__ acc,
                                     float* __restrict__ out) {
    out[0] = acc[0] * (1.f / (10.f * (float)B_ROWS))
           + OVERLAP_WEIGHT * (1.f - acc[1] * (1.f / (float)B_ROWS));
}

extern "C" void kernel_launch(void* const* d_in, const int* in_sizes, int n_in,
                              void* d_out, int out_size, void* d_ws, size_t ws_size,
                              hipStream_t stream) {
    const float4* preds4   = (const float4*)d_in[0];
    const float4* targets4 = (const float4*)d_in[1];
    float* out = (float*)d_out;
    float* acc = (float*)d_ws;

    hipMemsetAsync(acc, 0, 2 * sizeof(float), stream);

    hybrid_loss_main<<<GRID, THREADS, 0, stream>>>(preds4, targets4, acc);
    hybrid_loss_finalize<<<1, 1, 0, stream>>>(acc, out);
}

// Round 13
// 190.605 us; speedup vs baseline: 1.1180x; 1.1180x over previous
//
#include <hip/hip_runtime.h>

// HybridLoss: param smooth-L1 mean + 0.5*(1 - mean(box overlap))
// B = 2,000,000 rows x 10 f32 (c[3], d[3], q[4]) per side.
//
// R3:  per-row direct loads -> 76us, transaction/latency-bound.
// R5:  gload_lds, no overlap -> 112us.
// R6:  reg-staged T14 pipeline -> RIGHT schedule (HBM% 35, best so far in
//      flight) but VGPR=52 forced spills (152 MB scratch), 97us.
// R10: runtime-indexed dbuf gload_lds -> vmcnt drains pre-compute, 73.5us.
// R11: static dbuf gload_lds -> same serialization, 98us. gload_lds is
//      un-overlappable at source level here.
// R12 (this): R6's schedule, spill-free. Dense float4 loads (lane-contig,
//      16 segs/instr) issued BEFORE compute; ds_write to the OTHER static
//      buffer AFTER compute (vmcnt wait sits post-compute by data dep);
//      only 24 VGPRs live across compute; __launch_bounds__(256,4) = 128
//      VGPR budget so nothing spills. Static even/odd buffers (rule #20).

#define B_ROWS 2000000
#define THREADS 256
#define CHUNK_ROWS 256
#define F4_SIDE 640                    // 256 rows * 40 B / 16 B per side
#define N_CHUNKS 7813                  // ceil(2e6 / 256); tail chunk = 128 rows
#define GRID 1024                      // persistent, 4 blocks/CU (40 KB LDS)
constexpr float OVERLAP_WEIGHT = 0.5f;
constexpr float EPS_F = 1e-6f;
constexpr int TOTAL_F4 = 5000000;      // per side

__device__ __forceinline__ void quat_to_rot(float x, float y, float z, float w,
                                            float R[9]) {
    R[0] = 1.f - 2.f*y*y - 2.f*z*z;
    R[1] = 2.f*x*y + 2.f*z*w;
    R[2] = 2.f*x*z - 2.f*y*w;
    R[3] = 2.f*x*y - 2.f*z*w;
    R[4] = 1.f - 2.f*x*x - 2.f*z*z;
    R[5] = 2.f*y*z + 2.f*x*w;
    R[6] = 2.f*x*z + 2.f*y*w;
    R[7] = 2.f*y*z - 2.f*x*w;
    R[8] = 1.f - 2.f*x*x - 2.f*y*y;
}

__global__ __launch_bounds__(THREADS, 4) void hybrid_loss_main(
    const float4* __restrict__ preds4, const float4* __restrict__ targets4,
    float* __restrict__ acc)  // acc[0] = smooth-L1 sum, acc[1] = overlap sum
{
    // static even/odd double buffer: 4 * 640 * 16 B = 40 KB -> 4 blocks/CU
    __shared__ __align__(16) float4 P0[F4_SIDE], T0[F4_SIDE];
    __shared__ __align__(16) float4 P1[F4_SIDE], T1[F4_SIDE];

    const int tid  = threadIdx.x;
    const int wave = tid >> 6;
    const int lane = tid & 63;
    const bool lo  = (tid < 128);

    float psum = 0.f, osum = 0.f;

    // prefetch registers: 6 float4 = 24 VGPRs live across compute
    float4 a0, a1, a2, b0, b1, b2;

    // dense lane-contiguous loads: each instr = 64 lanes x 16 B contiguous
    auto LD = [&](int c) {
        const int gb = c * F4_SIDE;
        int i0 = gb + tid;        if (i0 >= TOTAL_F4) i0 = TOTAL_F4 - 1;
        int i1 = gb + 256 + tid;  if (i1 >= TOTAL_F4) i1 = TOTAL_F4 - 1;
        a0 = preds4[i0];   a1 = preds4[i1];
        b0 = targets4[i0]; b1 = targets4[i1];
        if (lo) {
            int i2 = gb + 512 + tid; if (i2 >= TOTAL_F4) i2 = TOTAL_F4 - 1;
            a2 = preds4[i2]; b2 = targets4[i2];
        }
    };
    // write-late: the s_waitcnt vmcnt for LD's results sits HERE (post-compute)
    auto WR = [&](float4* P, float4* T) {
        P[tid] = a0;       P[256 + tid] = a1;
        T[tid] = b0;       T[256 + tid] = b1;
        if (lo) { P[512 + tid] = a2; T[512 + tid] = b2; }
    };

    auto compute = [&](const float4* LP4, const float4* LT4, int c) {
        if (c * CHUNK_ROWS + tid < B_ROWS) {
            float p[10], t[10];
            const float2* lp = reinterpret_cast<const float2*>(
                reinterpret_cast<const float*>(LP4) + tid * 10);
            const float2* lt = reinterpret_cast<const float2*>(
                reinterpret_cast<const float*>(LT4) + tid * 10);
            #pragma unroll
            for (int i = 0; i < 5; ++i) {
                float2 a = lp[i]; p[2*i] = a.x; p[2*i+1] = a.y;
                float2 b = lt[i]; t[2*i] = b.x; t[2*i+1] = b.y;
            }

            // smooth L1
            #pragma unroll
            for (int i = 0; i < 10; ++i) {
                float d  = p[i] - t[i];
                float ad = fabsf(d);
                psum += (ad < 1.f) ? 0.5f * d * d : ad - 0.5f;
            }

            // overlap
            float pqn = sqrtf(p[6]*p[6] + p[7]*p[7] + p[8]*p[8] + p[9]*p[9]);
            float tqn = sqrtf(t[6]*t[6] + t[7]*t[7] + t[8]*t[8] + t[9]*t[9]);
            float pri = 1.f / pqn, tri = 1.f / tqn;
            float PR[9], TR[9];
            quat_to_rot(p[6]*pri, p[7]*pri, p[8]*pri, p[9]*pri, PR);
            quat_to_rot(t[6]*tri, t[7]*tri, t[8]*tri, t[9]*tri, TR);

            float ra = 0.f;
            #pragma unroll
            for (int i = 0; i < 9; ++i) ra += PR[i] * TR[i];
            ra = fminf(fmaxf(ra * (1.f/3.f), 0.f), 1.f);

            float ov = ra;
            #pragma unroll
            for (int i = 0; i < 3; ++i) {
                float pe = fabsf(PR[3*i+0]*(p[3]*0.5f) + PR[3*i+1]*(p[4]*0.5f) + PR[3*i+2]*(p[5]*0.5f));
                float te = fabsf(TR[3*i+0]*(t[3]*0.5f) + TR[3*i+1]*(t[4]*0.5f) + TR[3*i+2]*(t[5]*0.5f));
                float cd = fabsf(p[i] - t[i]);
                float ax = fmaxf(fminf(pe, te) * 2.f - cd, 0.f) / (pe + te + EPS_F);
                ov *= ax;
            }
            ov = fminf(fmaxf(ov, 0.f), 1.f);
            osum += ov;
        }
    };

    // ---- prologue: fill buf0 with chunk cc ----
    int cc = blockIdx.x;
    LD(cc);
    WR(P0, T0);
    __syncthreads();

    // ---- T14 pipeline, static even/odd, all barriers block-uniform ----
    for (;;) {
        int cn = cc + GRID;
        bool more = (cn < N_CHUNKS);
        if (more) LD(cn);                 // issue-early
        compute(P0, T0, cc);              // overlap: loads in flight
        if (more) WR(P1, T1);             // write-late (vmcnt waits here)
        __syncthreads();
        if (!more) break;
        cc = cn;

        cn = cc + GRID;
        more = (cn < N_CHUNKS);
        if (more) LD(cn);
        compute(P1, T1, cc);
        if (more) WR(P0, T0);
        __syncthreads();
        if (!more) break;
        cc = cn;
    }

    // ---- reduction: wave shuffle, cross-wave via reused LDS ----
    #pragma unroll
    for (int off = 32; off > 0; off >>= 1) {
        psum += __shfl_down(psum, off);
        osum += __shfl_down(osum, off);
    }
    __syncthreads();                      // compute phase fully done
    float* red = reinterpret_cast<float*>(P0);
    if (lane == 0) { red[wave] = psum; red[4 + wave] = osum; }
    __syncthreads();
    if (tid == 0) {
        atomicAdd(&acc[0], red[0] + red[1] + red[2] + red[3]);
        atomicAdd(&acc[1], red[4] + red[5] + red[6] + red[7]);
    }
}

__global__ void hybrid_loss_finalize(const float* __restrict__ acc,
                                     float* __restrict__ out) {
    out[0] = acc[0] * (1.f / (10.f * (float)B_ROWS))
           + OVERLAP_WEIGHT * (1.f - acc[1] * (1.f / (float)B_ROWS));
}

extern "C" void kernel_launch(void* const* d_in, const int* in_sizes, int n_in,
                              void* d_out, int out_size, void* d_ws, size_t ws_size,
                              hipStream_t stream) {
    const float4* preds4   = (const float4*)d_in[0];
    const float4* targets4 = (const float4*)d_in[1];
    float* out = (float*)d_out;
    float* acc = (float*)d_ws;

    hipMemsetAsync(acc, 0, 2 * sizeof(float), stream);

    hybrid_loss_main<<<GRID, THREADS, 0, stream>>>(preds4, targets4, acc);
    hybrid_loss_finalize<<<1, 1, 0, stream>>>(acc, out);
}